// Round 3
// baseline (476.305 us; speedup 1.0000x reference)
//
#include <hip/hip_runtime.h>
#include <hip/hip_cooperative_groups.h>

namespace cg = cooperative_groups;

// EmotionCaps dynamic routing (fp32 I/O):
// u: [B=64, N=1024, I=64] f32; W: [N=1024, E=8, O=32, I=64] f32
// out: v [B=64, E=8, O=32] f32
// Stage 1: u_hat = per-n GEMM via bf16 MFMA, stored bf16 (32 MB ws).
// Stage 2: all 3 routing iterations in ONE cooperative kernel, u_hat tile in LDS.

#define B_  64
#define N_  1024
#define I_  64
#define E_  8
#define O_  32
#define EO_ 256

typedef __bf16 bf16x8 __attribute__((ext_vector_type(8)));
typedef float  f32x4  __attribute__((ext_vector_type(4)));

__device__ __forceinline__ float bf2f(unsigned int h) {
    unsigned int x = (h & 0xffffu) << 16;
    return __builtin_bit_cast(float, x);
}
__device__ __forceinline__ unsigned short f2bf(float f) {
    unsigned int x = __builtin_bit_cast(unsigned int, f);
    unsigned int r = x + 0x7fffu + ((x >> 16) & 1u);   // RNE
    return (unsigned short)(r >> 16);
}
__device__ __forceinline__ bf16x8 cvt8(const float* __restrict__ p) {
    float4 q0 = *(const float4*)p;
    float4 q1 = *(const float4*)(p + 4);
    bf16x8 a;
    a[0] = (__bf16)q0.x; a[1] = (__bf16)q0.y; a[2] = (__bf16)q0.z; a[3] = (__bf16)q0.w;
    a[4] = (__bf16)q1.x; a[5] = (__bf16)q1.y; a[6] = (__bf16)q1.z; a[7] = (__bf16)q1.w;
    return a;
}

// ---------------------------------------------------------------------------
// K1: one block per n. Per-n GEMM: u_hat[b,eo] = u[b,:] . W[eo,:]  (K=64)
// A = u (M=64 rows b), B = W^T (N=256 cols eo), bf16 MFMA 16x16x32, K-steps=2.
// Wave w owns eo in [64w, 64w+64) = n-tiles 4w..4w+3; all 4 m-tiles.
// Fragments loaded directly from global with fp32->bf16 convert (no LDS).
//   A lane map: row m=lane&15, k=(lane>>4)*8+j    [guide §3, m89/m120-verified]
//   B lane map: col n=lane&15, k=(lane>>4)*8+j
//   D lane map: col=lane&15, row=(lane>>4)*4+reg
// ---------------------------------------------------------------------------
__global__ __launch_bounds__(256) void k_uhat(const float* __restrict__ u,
                                              const float* __restrict__ W,
                                              unsigned short* __restrict__ uh) {
    const int n = blockIdx.x;
    const int t = threadIdx.x;
    const int w = t >> 6, l = t & 63;
    const int m16 = l & 15, g = l >> 4;

    bf16x8 afr[4][2];
#pragma unroll
    for (int mt = 0; mt < 4; ++mt) {
        const float* up = u + (size_t)(mt * 16 + m16) * (N_ * I_) + n * I_ + g * 8;
#pragma unroll
        for (int ks = 0; ks < 2; ++ks) afr[mt][ks] = cvt8(up + ks * 32);
    }
#pragma unroll
    for (int nt = 0; nt < 4; ++nt) {
        const int eo = w * 64 + nt * 16 + m16;
        const float* wp = W + (size_t)n * (EO_ * I_) + (size_t)eo * I_ + g * 8;
        bf16x8 bfr0 = cvt8(wp);
        bf16x8 bfr1 = cvt8(wp + 32);
#pragma unroll
        for (int mt = 0; mt < 4; ++mt) {
            f32x4 acc = {0.f, 0.f, 0.f, 0.f};
            acc = __builtin_amdgcn_mfma_f32_16x16x32_bf16(afr[mt][0], bfr0, acc, 0, 0, 0);
            acc = __builtin_amdgcn_mfma_f32_16x16x32_bf16(afr[mt][1], bfr1, acc, 0, 0, 0);
#pragma unroll
            for (int r = 0; r < 4; ++r) {
                int b = mt * 16 + g * 4 + r;
                uh[(size_t)b * (N_ * EO_) + (size_t)n * EO_ + eo] = f2bf(acc[r]);
            }
        }
    }
}

// ---------------------------------------------------------------------------
// K2 (cooperative, 1024 blocks = (b, chunk of 64 n), 4 blocks/CU co-resident):
// u_hat tile (64n x 256eo bf16 = 32KB) staged in LDS once; 3 routing
// iterations with in-wave shuffle softmax (verified round 2); s reduced via
// race-free per-iteration partials sp[it][blk][eo] + grid.sync(); squash
// computed redundantly per block; chunk==0 blocks write the output.
// LDS: 32768 + 1024 + 2048 + 4096 = 39936 B  (4 x <=40KB per CU OK)
// ---------------------------------------------------------------------------
__global__ __launch_bounds__(256, 4) void k_route_fused(
        const unsigned short* __restrict__ uh,
        float* __restrict__ sp,
        float* __restrict__ out) {
    const int blk = blockIdx.x;
    const int b = blk >> 4, chunk = blk & 15;
    const int t = threadIdx.x, wave = t >> 6, l = t & 63;
    const int e = l >> 3;
    cg::grid_group grid = cg::this_grid();

    __shared__ __align__(16) unsigned short tile[64 * EO_];  // 32 KB bf16
    __shared__ __align__(16) float vlds[EO_];                //  1 KB
    __shared__ __align__(16) float blog[64 * E_];            //  2 KB logits
    __shared__ __align__(16) float red[4][EO_];              //  4 KB

    {   // stage u_hat[b, chunk*64 .. +63, :] -> LDS (coalesced uint4)
        const uint4* src = (const uint4*)(uh + (size_t)b * (N_ * EO_)
                                             + (size_t)chunk * 64 * EO_);
        uint4* dst = (uint4*)tile;
#pragma unroll
        for (int j = 0; j < 8; ++j) dst[t + 256 * j] = src[t + 256 * j];
    }
    __syncthreads();

    float vv = 0.f;
#pragma unroll 1
    for (int it = 0; it < 3; ++it) {
        float4 v4 = make_float4(0.f, 0.f, 0.f, 0.f);
        if (it) v4 = *(const float4*)&vlds[4 * l];
        float a0 = 0.f, a1 = 0.f, a2 = 0.f, a3 = 0.f;
#pragma unroll 1
        for (int nn = 0; nn < 16; ++nn) {
            const int nl = wave * 16 + nn;
            uint2 p = *(const uint2*)(tile + nl * EO_ + 4 * l);
            float x0 = bf2f(p.x), x1 = bf2f(p.x >> 16);
            float x2 = bf2f(p.y), x3 = bf2f(p.y >> 16);
            float c;
            if (it == 0) {
                c = 0.125f;
            } else {
                float pd = x0 * v4.x + x1 * v4.y + x2 * v4.z + x3 * v4.w;
                pd += __shfl_xor(pd, 1);
                pd += __shfl_xor(pd, 2);
                pd += __shfl_xor(pd, 4);          // uv[e] in all 8 lanes of group
                float logit = pd;
                if (it == 2) logit += blog[nl * E_ + e];
                else if ((l & 7) == 0) blog[nl * E_ + e] = logit;
                float m = logit;
                m = fmaxf(m, __shfl_xor(m, 8));
                m = fmaxf(m, __shfl_xor(m, 16));
                m = fmaxf(m, __shfl_xor(m, 32));
                float ex = __expf(logit - m);
                float sm = ex;
                sm += __shfl_xor(sm, 8);
                sm += __shfl_xor(sm, 16);
                sm += __shfl_xor(sm, 32);
                c = ex / sm;
            }
            a0 = fmaf(c, x0, a0); a1 = fmaf(c, x1, a1);
            a2 = fmaf(c, x2, a2); a3 = fmaf(c, x3, a3);
        }
        __syncthreads();                              // red free for reuse
        *(float4*)&red[wave][4 * l] = make_float4(a0, a1, a2, a3);
        __syncthreads();
        float tot = red[0][t] + red[1][t] + red[2][t] + red[3][t];
        sp[(size_t)it * (1024 * EO_) + blk * EO_ + t] = tot;
        grid.sync();
        // gather partials + squash (redundant per block, for its b)
        const float* spi = sp + (size_t)it * (1024 * EO_);
        float sv = 0.f;
#pragma unroll
        for (int cI = 0; cI < 16; ++cI) sv += spi[(b * 16 + cI) * EO_ + t];
        float sq = sv * sv;
        sq += __shfl_xor(sq, 1);
        sq += __shfl_xor(sq, 2);
        sq += __shfl_xor(sq, 4);
        sq += __shfl_xor(sq, 8);
        sq += __shfl_xor(sq, 16);     // |s|^2 over o-group (32 lanes = one e)
        float nrm = sqrtf(sq);
        vv = sq / ((1.f + sq) * (nrm + 1e-8f)) * sv;
        if (it < 2) vlds[t] = vv;
        __syncthreads();              // v visible before next iteration
    }
    if (chunk == 0) out[b * EO_ + t] = vv;
}

extern "C" void kernel_launch(void* const* d_in, const int* in_sizes, int n_in,
                              void* d_out, int out_size, void* d_ws, size_t ws_size,
                              hipStream_t stream) {
    const float* u = (const float*)d_in[0];     // f32 [64,1024,64]
    const float* W = (const float*)d_in[1];     // f32 [1024,8,32,64]
    float* out = (float*)d_out;                 // f32 [64,8,32]

    char* ws = (char*)d_ws;
    unsigned short* uh = (unsigned short*)ws;        // 33,554,432 B  u_hat bf16
    float* sp = (float*)(ws + 33554432);             //  3,145,728 B  s partials x3

    k_uhat<<<dim3(N_), dim3(256), 0, stream>>>(u, W, uh);

    void* args[] = { (void*)&uh, (void*)&sp, (void*)&out };
    hipLaunchCooperativeKernel((void*)k_route_fused, dim3(1024), dim3(256),
                               args, 0, stream);
}

// Round 4
// 143.069 us; speedup vs baseline: 3.3292x; 3.3292x over previous
//
#include <hip/hip_runtime.h>

// EmotionCaps dynamic routing (fp32 I/O):
// u: [B=64, N=1024, I=64] f32; W: [N=1024, E=8, O=32, I=64] f32
// out: v [B=64, E=8, O=32] f32
// Stage 1: u_hat (bf16, 32MB ws) = per-n GEMM via bf16 MFMA, LDS-staged.
// Stage 2: 3 routing passes, no cooperative launch (grid.sync measured
//          ~110us/sync in round 3 — abandoned). Logits never stored:
//          b1 = uhat.v0 ; b2 = uhat.(v0+v1)  (exact identity).

#define B_  64
#define N_  1024
#define I_  64
#define E_  8
#define O_  32
#define EO_ 256
#define PAD_ 72    // padded LDS row (bf16 elems): stride 144B = 36 dwords -> 2-way banks (free)

typedef __bf16 bf16x8 __attribute__((ext_vector_type(8)));
typedef __bf16 bf16x4v __attribute__((ext_vector_type(4)));
typedef float  f32x4  __attribute__((ext_vector_type(4)));

__device__ __forceinline__ float bf2f(unsigned int h) {
    unsigned int x = (h & 0xffffu) << 16;
    return __builtin_bit_cast(float, x);
}
__device__ __forceinline__ unsigned short f2bf(float f) {
    unsigned int x = __builtin_bit_cast(unsigned int, f);
    unsigned int r = x + 0x7fffu + ((x >> 16) & 1u);   // RNE
    return (unsigned short)(r >> 16);
}
__device__ __forceinline__ void cvt_store4(unsigned short* dst, float4 q) {
    bf16x4v v;
    v[0] = (__bf16)q.x; v[1] = (__bf16)q.y; v[2] = (__bf16)q.z; v[3] = (__bf16)q.w;
    *(bf16x4v*)dst = v;
}

// ---------------------------------------------------------------------------
// K1: one block per n. D[64b x 256eo] = u[:,n,:] . W[n]^T via 16x16x32 bf16
// MFMA (fragment layouts verified correct in round 3: same absmax as VALU).
// All global traffic coalesced; LDS rows padded (PAD_) for frag reads;
// epilogue transposes through LDS (reusing Wl) for uint2 stores.
// LDS: Wl 36864 + ul 9216 = 46080 B -> 3 blocks/CU.
// ---------------------------------------------------------------------------
__global__ __launch_bounds__(256) void k_uhat(const float* __restrict__ u,
                                              const float* __restrict__ W,
                                              unsigned short* __restrict__ uh) {
    const int n = blockIdx.x;
    const int t = threadIdx.x;
    const int w = t >> 6, l = t & 63;
    const int m16 = l & 15, g = l >> 4;

    __shared__ __align__(16) unsigned short Wl[EO_ * PAD_]; // 36864 B (reused as D-tile)
    __shared__ __align__(16) unsigned short ul[B_ * PAD_];  //  9216 B

    // stage W[n]: 4096 float4, coalesced; convert to bf16
    {
        const float* Wg = W + (size_t)n * (EO_ * I_);
#pragma unroll
        for (int j = 0; j < 16; ++j) {
            int idx = j * 256 + t;                 // float4 index
            int eo = idx >> 4, c = idx & 15;
            float4 q = *(const float4*)(Wg + idx * 4);
            cvt_store4(&Wl[eo * PAD_ + c * 4], q);
        }
    }
    // stage u[:, n, :]: 1024 float4
    {
#pragma unroll
        for (int j = 0; j < 4; ++j) {
            int idx = j * 256 + t;
            int b = idx >> 4, c = idx & 15;
            float4 q = *(const float4*)(u + (size_t)b * (N_ * I_) + n * I_ + c * 4);
            cvt_store4(&ul[b * PAD_ + c * 4], q);
        }
    }
    __syncthreads();

    // A fragments (u rows), resident: A[m][k], m=lane&15, k=(lane>>4)*8+j
    bf16x8 afr[4][2];
#pragma unroll
    for (int mt = 0; mt < 4; ++mt)
#pragma unroll
        for (int ks = 0; ks < 2; ++ks)
            afr[mt][ks] = *(const bf16x8*)&ul[(mt * 16 + m16) * PAD_ + ks * 32 + g * 8];

    f32x4 acc[4][4];
#pragma unroll
    for (int nt = 0; nt < 4; ++nt)
#pragma unroll
        for (int mt = 0; mt < 4; ++mt)
            acc[nt][mt] = (f32x4){0.f, 0.f, 0.f, 0.f};

#pragma unroll
    for (int nt = 0; nt < 4; ++nt) {
        const int eo = w * 64 + nt * 16 + m16;
        bf16x8 b0 = *(const bf16x8*)&Wl[eo * PAD_ + g * 8];
        bf16x8 b1 = *(const bf16x8*)&Wl[eo * PAD_ + 32 + g * 8];
#pragma unroll
        for (int mt = 0; mt < 4; ++mt) {
            acc[nt][mt] = __builtin_amdgcn_mfma_f32_16x16x32_bf16(afr[mt][0], b0, acc[nt][mt], 0, 0, 0);
            acc[nt][mt] = __builtin_amdgcn_mfma_f32_16x16x32_bf16(afr[mt][1], b1, acc[nt][mt], 0, 0, 0);
        }
    }

    // epilogue: D lane map col=lane&15, row=(lane>>4)*4+reg -> LDS tile
    __syncthreads();                     // all waves done reading Wl
    unsigned short* uhl = Wl;            // reuse: 64 rows x 264 (pad+8) = 33792 B
#pragma unroll
    for (int nt = 0; nt < 4; ++nt) {
        const int col = w * 64 + nt * 16 + m16;
#pragma unroll
        for (int mt = 0; mt < 4; ++mt)
#pragma unroll
            for (int r = 0; r < 4; ++r)
                uhl[(mt * 16 + g * 4 + r) * 264 + col] = f2bf(acc[nt][mt][r]);
    }
    __syncthreads();
    // store: 64 rows x 512B contiguous runs (uint2 per lane)
#pragma unroll
    for (int r = 0; r < 16; ++r) {
        const int row = r * 4 + w;
        uint2 q = *(const uint2*)&uhl[row * 264 + l * 4];
        *(uint2*)(uh + (size_t)row * (N_ * EO_) + (size_t)n * EO_ + l * 4) = q;
    }
}

// ---------------------------------------------------------------------------
// K2: one routing pass. Block = (b, chunk of 32 n); wave handles 8 n.
// Lane l owns eo = 4l..4l+3 (e=l>>3). In-wave shuffle softmax (verified r2/r3):
//   dot over o: shfl_xor 1,2,4 ; softmax over E: shfl_xor 8,16,32.
// mode 0: c = 1/8. mode 1: logit = uhat.vin (vin = v0 or v0+v1).
// Output: race-free partials sp[blk][eo].
// ---------------------------------------------------------------------------
__global__ __launch_bounds__(256) void k_route(const unsigned short* __restrict__ uh,
                                               const float* __restrict__ vin,
                                               float* __restrict__ sp,
                                               int mode) {
    const int blk = blockIdx.x;
    const int b = blk >> 5, chunk = blk & 31;
    const int t = threadIdx.x, wave = t >> 6, l = t & 63;

    float4 v4 = make_float4(0.f, 0.f, 0.f, 0.f);
    if (mode) v4 = *(const float4*)(vin + b * EO_ + 4 * l);

    float a0 = 0.f, a1 = 0.f, a2 = 0.f, a3 = 0.f;
    const int n0 = chunk * 32 + wave * 8;
#pragma unroll 1
    for (int nn = 0; nn < 8; ++nn) {
        const int n = n0 + nn;
        uint2 p = *(const uint2*)(uh + (size_t)b * (N_ * EO_) + (size_t)n * EO_ + 4 * l);
        float x0 = bf2f(p.x), x1 = bf2f(p.x >> 16);
        float x2 = bf2f(p.y), x3 = bf2f(p.y >> 16);
        float c;
        if (mode == 0) {
            c = 0.125f;
        } else {
            float pd = x0 * v4.x + x1 * v4.y + x2 * v4.z + x3 * v4.w;
            pd += __shfl_xor(pd, 1);
            pd += __shfl_xor(pd, 2);
            pd += __shfl_xor(pd, 4);          // logit = uhat.v for this (n,e)
            float m = pd;
            m = fmaxf(m, __shfl_xor(m, 8));
            m = fmaxf(m, __shfl_xor(m, 16));
            m = fmaxf(m, __shfl_xor(m, 32));
            float ex = __expf(pd - m);
            float sm = ex;
            sm += __shfl_xor(sm, 8);
            sm += __shfl_xor(sm, 16);
            sm += __shfl_xor(sm, 32);
            c = ex / sm;
        }
        a0 = fmaf(c, x0, a0); a1 = fmaf(c, x1, a1);
        a2 = fmaf(c, x2, a2); a3 = fmaf(c, x3, a3);
    }

    __shared__ __align__(16) float red[4][EO_];
    *(float4*)&red[wave][4 * l] = make_float4(a0, a1, a2, a3);
    __syncthreads();
    sp[(size_t)blk * EO_ + t] = red[0][t] + red[1][t] + red[2][t] + red[3][t];
}

// ---------------------------------------------------------------------------
// K3: reduce partials (32 per (b,eo)), squash over o (shfl 1..16), and
// maintain vwork: it0 -> vsum=v0, vwork=v0 ; it1 -> vwork=v0+v1 ; it2 -> out.
// ---------------------------------------------------------------------------
__global__ __launch_bounds__(256) void k_squash(const float* __restrict__ sp,
                                                float* __restrict__ vsum,
                                                float* __restrict__ vwork,
                                                float* __restrict__ out,
                                                int it) {
    const int b = blockIdx.x, t = threadIdx.x;   // t = eo
    float sv = 0.f;
#pragma unroll
    for (int ci = 0; ci < 32; ++ci) sv += sp[(size_t)(b * 32 + ci) * EO_ + t];
    float sq = sv * sv;
    sq += __shfl_xor(sq, 1);
    sq += __shfl_xor(sq, 2);
    sq += __shfl_xor(sq, 4);
    sq += __shfl_xor(sq, 8);
    sq += __shfl_xor(sq, 16);                    // |s|^2 over o (32-lane group)
    float nrm = sqrtf(sq);
    float vv = sq / ((1.f + sq) * (nrm + 1e-8f)) * sv;
    if (it == 0)      { vsum[b * EO_ + t] = vv; vwork[b * EO_ + t] = vv; }
    else if (it == 1) { vwork[b * EO_ + t] = vsum[b * EO_ + t] + vv; }
    else              { out[b * EO_ + t] = vv; }
}

extern "C" void kernel_launch(void* const* d_in, const int* in_sizes, int n_in,
                              void* d_out, int out_size, void* d_ws, size_t ws_size,
                              hipStream_t stream) {
    const float* u = (const float*)d_in[0];     // f32 [64,1024,64]
    const float* W = (const float*)d_in[1];     // f32 [1024,8,32,64]
    float* out = (float*)d_out;                 // f32 [64,8,32]

    char* ws = (char*)d_ws;
    unsigned short* uh = (unsigned short*)ws;        // 33,554,432 B  u_hat bf16
    float* sp    = (float*)(ws + 33554432);          //  2,097,152 B  partials
    float* vsum  = (float*)(ws + 35651584);          //     65,536 B
    float* vwork = (float*)(ws + 35717120);          //     65,536 B

    k_uhat  <<<dim3(N_),   dim3(256), 0, stream>>>(u, W, uh);
    k_route <<<dim3(2048), dim3(256), 0, stream>>>(uh, vwork, sp, 0);
    k_squash<<<dim3(B_),   dim3(256), 0, stream>>>(sp, vsum, vwork, out, 0);
    k_route <<<dim3(2048), dim3(256), 0, stream>>>(uh, vwork, sp, 1);
    k_squash<<<dim3(B_),   dim3(256), 0, stream>>>(sp, vsum, vwork, out, 1);
    k_route <<<dim3(2048), dim3(256), 0, stream>>>(uh, vwork, sp, 1);
    k_squash<<<dim3(B_),   dim3(256), 0, stream>>>(sp, vsum, vwork, out, 2);
}